// Round 15
// baseline (6113.870 us; speedup 1.0000x reference)
//
#include <hip/hip_runtime.h>
#include <stdint.h>

// Echo-state network (fp32 in, fp32 out). Round 29: persistent kernel with
// per-group atomic barriers around the VERBATIM R23 step body (1511 us).
// R28 post-mortem: 32x32-MFMA retile collapsed occupancy (13%) -> refuted;
// every throughput-shape lever is now refuted and R23 stands. Last untried
// cost: 70 serially-dependent launches (~150-250 us of launch/drain/refill).
// Structural fact: s_new[b,n,:] depends only on s[b,n,:] -> the 768 blocks
// split into 24 INDEPENDENT closed groups of 32 (group=(b,mt): its it-blocks
// produce exactly the state rows they consume). So inter-step sync is
// group-wide, not grid-wide: ONE plain launch (graph-safe; R17's cooperative
// API is not), t-loop inside, and between steps a 32-block generation
// barrier: __syncthreads (drains stores to L2) -> thread0 __threadfence +
// release fetch_add on group counter -> acquire-load spin (s_sleep backoff)
// to 32*(t+1) -> __syncthreads. Device-scope atomics + compiler cache ops
// give cross-XCD visibility. Co-residency guaranteed: 48 KB LDS -> exactly
// 3 blocks/CU x 256 CU = 768 = grid (VGPR ~68 << 170) -> no deadlock at
// correct occupancy. Step body, staging (GLOAD16 2-deep dbuf, XOR swizzle
// both sides), R18 XCD swizzle, epilogue, head partials, head_reduce are
// byte-identical to R23 -> bit-identical numerics.

typedef _Float16 f16;
typedef _Float16 f16x8 __attribute__((ext_vector_type(8)));
typedef float floatx4 __attribute__((ext_vector_type(4)));

#define N_TOT 256
#define T_TOT 70
#define V_TOT 64
#define B_TOT 6
#define H_TOT 1024
#define C_TOT 4
#define F_TOT (B_TOT * H_TOT)
#define G_TOT 192       // partial groups = B_TOT * 32 unit-tiles
#define LO_SCALE 4096.0f
#define LO_INV   (1.0f / 4096.0f)

union H8 { f16 h[8]; uint4 v; };

// global->LDS DMA, 16 B per lane. LDS dest = wave-uniform base + lane*16.
#define GLOAD16(g, l)                                                        \
    __builtin_amdgcn_global_load_lds(                                        \
        (const __attribute__((address_space(1))) void*)(g),                  \
        (__attribute__((address_space(3))) void*)(l), 16, 0, 0)

// ---------------------------------------------------------------------------
// Zero the 24 group-barrier counters (16-int spacing = 64 B anti-false-share).
// ---------------------------------------------------------------------------
__global__ __launch_bounds__(384)
void zero_bar(int* __restrict__ bar)
{
    bar[threadIdx.x] = 0;
}

// ---------------------------------------------------------------------------
// One-time fp32 -> (hi, lo*4096) f16 split, 8 elems/thread. n % 2048 == 0.
// ---------------------------------------------------------------------------
__global__ __launch_bounds__(256)
void split_f32(const float* __restrict__ src, f16* __restrict__ hi,
               f16* __restrict__ lo, int n)
{
    const int i = (blockIdx.x * 256 + threadIdx.x) * 8;
    if (i + 8 > n) return;
    const float4 a = *(const float4*)&src[i];
    const float4 b = *(const float4*)&src[i + 4];
    const float x[8] = {a.x, a.y, a.z, a.w, b.x, b.y, b.z, b.w};
    H8 H, L;
#pragma unroll
    for (int j = 0; j < 8; ++j) {
        const f16 h = (f16)x[j];
        H.h[j] = h;
        L.h[j] = (f16)((x[j] - (float)h) * LO_SCALE);
    }
    *(uint4*)&hi[i] = H.v;
    *(uint4*)&lo[i] = L.v;
}

// ---------------------------------------------------------------------------
// Final head reduce + argmax. Block = t (70), thread = n (256).
// ---------------------------------------------------------------------------
__global__ __launch_bounds__(256)
void head_reduce(const float* __restrict__ part,
                 const float* __restrict__ b_lin,
                 float* __restrict__ logits,
                 float* __restrict__ preds)
{
    const int t = blockIdx.x;
    const int n = threadIdx.x;

    float a0 = b_lin[t * C_TOT + 0];
    float a1 = b_lin[t * C_TOT + 1];
    float a2 = b_lin[t * C_TOT + 2];
    float a3 = b_lin[t * C_TOT + 3];

    const float* p = part + (((size_t)t * G_TOT) * N_TOT + n) * C_TOT;
    for (int g = 0; g < G_TOT; ++g) {
        const float4 v = *(const float4*)&p[(size_t)g * N_TOT * C_TOT];
        a0 += v.x; a1 += v.y; a2 += v.z; a3 += v.w;
    }

    float4 o = {a0, a1, a2, a3};
    *(float4*)&logits[((size_t)t * N_TOT + n) * C_TOT] = o;

    int arg = 0;
    float best = a0;
    if (a1 > best) { best = a1; arg = 1; }
    if (a2 > best) { best = a2; arg = 2; }
    if (a3 > best) { best = a3; arg = 3; }
    preds[(size_t)t * N_TOT + n] = (float)arg;
}

// ---------------------------------------------------------------------------
// Persistent fused step+head: for t in [0,70): S_new = tanh(S W_res^T +
// X_t W_in^T); head partials -> part[]; per-(b,mt)-group atomic barrier
// between steps. Tile 64(M) x 32(I); grid = 768 = exactly 3 blocks/CU
// (48 KB LDS) -> all co-resident. Body verbatim R23: 17 chunks of K=64,
// GLOAD16 into 2-deep LDS dbuf, 1 __syncthreads/chunk, XOR swizzle.
// ---------------------------------------------------------------------------
__global__ __launch_bounds__(256)
void esn_persist(const f16* __restrict__ Xhi,   const f16* __restrict__ Xlo,
                 const f16* __restrict__ Whi,   const f16* __restrict__ Wlo,
                 const f16* __restrict__ Wihi,  const f16* __restrict__ Wilo,
                 f16* __restrict__ sAh,         f16* __restrict__ sAl,
                 f16* __restrict__ sBh,         f16* __restrict__ sBl,
                 const float* __restrict__ W_lin, float* __restrict__ part,
                 int* __restrict__ bar)
{
    __shared__ f16 As_hi[2][64 * 64];
    __shared__ f16 As_lo[2][64 * 64];
    __shared__ f16 Bs_hi[2][32 * 64];
    __shared__ f16 Bs_lo[2][32 * 64];

    // R18 XCD-aware bijective swizzle (768 % 8 == 0), (b,it,mt)-major.
    const int p   = blockIdx.x;
    const int l   = (p & 7) * 96 + (p >> 3);
    const int mt  = l & 3;           // batch tile 0..3  (64 rows)
    const int bi  = l >> 2;          // 0..191
    const int b   = bi >> 5;         // reservoir block 0..5
    const int it  = bi & 31;         // unit tile 0..31  (32 cols)

    const int tid  = threadIdx.x;
    const int w    = tid >> 6;       // wave = M-quadrant
    const int lane = tid & 63;
    const int l16  = lane & 15;
    const int oct  = lane >> 4;
    const int r8   = lane >> 3;      // stripe row 0..7
    const int sw   = ((lane & 7) ^ r8) << 3;   // swizzled source col (f16)

    // LDS stripe bases (f16 elems) - wave-uniform
    const int dA0 = (w * 16) * 64;
    const int dA1 = (w * 16 + 8) * 64;
    const int dB  = (w * 8) * 64;

    // per-lane global row indices
    const int arow0 = mt * 64 + w * 16 + r8;   // A rows, issue 0
    const int arow1 = arow0 + 8;               // A rows, issue 1
    const int brow  = it * 32 + w * 8 + r8;    // B rows

    // t-invariant source pointers (per-lane, 16B-aligned)
    const f16* Bh0  = Whi  + (size_t)(b * H_TOT + brow) * H_TOT + sw;
    const f16* Bl0  = Wlo  + (size_t)(b * H_TOT + brow) * H_TOT + sw;
    const f16* Wih  = Wihi + (size_t)(b * H_TOT + brow) * V_TOT + sw;
    const f16* Wil  = Wilo + (size_t)(b * H_TOT + brow) * V_TOT + sw;
    const f16* Xh0b = Xhi + (size_t)arow0 * T_TOT * V_TOT + sw;
    const f16* Xh1b = Xhi + (size_t)arow1 * T_TOT * V_TOT + sw;
    const f16* Xl0b = Xlo + (size_t)arow0 * T_TOT * V_TOT + sw;
    const f16* Xl1b = Xlo + (size_t)arow1 * T_TOT * V_TOT + sw;

    // swizzled ds_read addresses (f16 elems); chunk-invariant.
    const int xsw = (l16 & 7) << 3;
    const int aoff[2] = {
        (w * 16 + l16) * 64 + ((0 + oct * 8) ^ xsw),
        (w * 16 + l16) * 64 + ((32 + oct * 8) ^ xsw)
    };
    int boff[2][2];
#pragma unroll
    for (int nf = 0; nf < 2; ++nf) {
        boff[nf][0] = (nf * 16 + l16) * 64 + ((0 + oct * 8) ^ xsw);
        boff[nf][1] = (nf * 16 + l16) * 64 + ((32 + oct * 8) ^ xsw);
    }

    const int nbase = mt * 64;
    const int ibase = it * 32;
    const int g     = b * 32 + it;
    int* cnt = bar + (b * 4 + mt) * 16;   // group counter (64 B spaced)

    for (int t = 0; t < T_TOT; ++t) {
        const f16* ph_hi = (t & 1) ? sBh : sAh;
        const f16* ph_lo = (t & 1) ? sBl : sAl;
        f16*       nx_hi = (t & 1) ? sAh : sBh;
        f16*       nx_lo = (t & 1) ? sAl : sBl;

        const f16* Ah0 = ph_hi + (size_t)(b * N_TOT + arow0) * H_TOT + sw;
        const f16* Ah1 = ph_hi + (size_t)(b * N_TOT + arow1) * H_TOT + sw;
        const f16* Al0 = ph_lo + (size_t)(b * N_TOT + arow0) * H_TOT + sw;
        const f16* Al1 = ph_lo + (size_t)(b * N_TOT + arow1) * H_TOT + sw;
        const f16* Xh0 = Xh0b + t * V_TOT;
        const f16* Xh1 = Xh1b + t * V_TOT;
        const f16* Xl0 = Xl0b + t * V_TOT;
        const f16* Xl1 = Xl1b + t * V_TOT;

        // stage chunk k into buffer k&1 (k==16 -> input term X / W_in)
        auto STAGE = [&](int k) {
            const int bb = k & 1;
            if (k < 16) {
                const size_t off = (size_t)k * 64;
                GLOAD16(Ah0 + off, &As_hi[bb][dA0]);
                GLOAD16(Ah1 + off, &As_hi[bb][dA1]);
                GLOAD16(Al0 + off, &As_lo[bb][dA0]);
                GLOAD16(Al1 + off, &As_lo[bb][dA1]);
                GLOAD16(Bh0 + off, &Bs_hi[bb][dB]);
                GLOAD16(Bl0 + off, &Bs_lo[bb][dB]);
            } else {
                GLOAD16(Xh0, &As_hi[bb][dA0]);
                GLOAD16(Xh1, &As_hi[bb][dA1]);
                GLOAD16(Xl0, &As_lo[bb][dA0]);
                GLOAD16(Xl1, &As_lo[bb][dA1]);
                GLOAD16(Wih, &Bs_hi[bb][dB]);
                GLOAD16(Wil, &Bs_lo[bb][dB]);
            }
        };

        floatx4 acc[2], accl[2];
#pragma unroll
        for (int j = 0; j < 2; ++j) { acc[j] = (floatx4)(0.0f); accl[j] = (floatx4)(0.0f); }

        const int kc0 = (t == 0) ? 16 : 0;
        STAGE(kc0);
        __syncthreads();   // vmcnt(0) drain: buffer kc0&1 ready

        for (int kc = kc0; kc <= 16; ++kc) {
            const int bb = kc & 1;
            if (kc < 16) STAGE(kc + 1);   // DMA next chunk into other buffer

#pragma unroll
            for (int half = 0; half < 2; ++half) {
                const f16x8 ah = *(const f16x8*)&As_hi[bb][aoff[half]];
                const f16x8 al = *(const f16x8*)&As_lo[bb][aoff[half]];
#pragma unroll
                for (int nf = 0; nf < 2; ++nf) {
                    const f16x8 bh = *(const f16x8*)&Bs_hi[bb][boff[nf][half]];
                    const f16x8 bl = *(const f16x8*)&Bs_lo[bb][boff[nf][half]];
                    acc[nf]  = __builtin_amdgcn_mfma_f32_16x16x32_f16(ah, bh, acc[nf], 0, 0, 0);
                    accl[nf] = __builtin_amdgcn_mfma_f32_16x16x32_f16(ah, bl, accl[nf], 0, 0, 0);
                    accl[nf] = __builtin_amdgcn_mfma_f32_16x16x32_f16(al, bh, accl[nf], 0, 0, 0);
                }
            }
            if (kc < 16) __syncthreads();   // next buffer DMA'd; this buffer free
        }

        // ---- epilogue: tanh -> split-store state; head partial -> part[] ----
        const float* wl = W_lin + (size_t)t * C_TOT * F_TOT + b * H_TOT + ibase;
        float wv[4][2];
#pragma unroll
        for (int c = 0; c < 4; ++c)
#pragma unroll
            for (int nf = 0; nf < 2; ++nf)
                wv[c][nf] = wl[(size_t)c * F_TOT + nf * 16 + l16];

        float sval[2][4];
#pragma unroll
        for (int nf = 0; nf < 2; ++nf)
#pragma unroll
            for (int r = 0; r < 4; ++r) {
                const int m  = w * 16 + oct * 4 + r;    // batch row within tile
                const int ii = nf * 16 + l16;           // unit col within tile
                const float s = tanhf(acc[nf][r] + accl[nf][r] * LO_INV);
                sval[nf][r] = s;
                const f16 h = (f16)s;
                const size_t oidx = (size_t)(b * N_TOT + nbase + m) * H_TOT + ibase + ii;
                nx_hi[oidx] = h;
                nx_lo[oidx] = (f16)((s - (float)h) * LO_SCALE);
            }

#pragma unroll
        for (int r = 0; r < 4; ++r) {
            float v[4];
#pragma unroll
            for (int c = 0; c < 4; ++c) {
                float x = sval[0][r] * wv[c][0] + sval[1][r] * wv[c][1];
                x += __shfl_xor(x, 1);
                x += __shfl_xor(x, 2);
                x += __shfl_xor(x, 4);
                x += __shfl_xor(x, 8);
                v[c] = x;
            }
            if (l16 == 0) {
                const int n = nbase + w * 16 + oct * 4 + r;
                float4 o = {v[0], v[1], v[2], v[3]};
                *(float4*)&part[(((size_t)t * G_TOT + g) * N_TOT + n) * C_TOT] = o;
            }
        }

        // ---- inter-step group barrier (32 blocks of (b,mt)) ----
        if (t < T_TOT - 1) {
            __syncthreads();   // drain all waves' stores (vmcnt0) + LDS reads
            if (tid == 0) {
                __threadfence();   // publish state stores device-wide
                __hip_atomic_fetch_add(cnt, 1, __ATOMIC_RELEASE,
                                       __HIP_MEMORY_SCOPE_AGENT);
                const int target = 32 * (t + 1);
                while (__hip_atomic_load(cnt, __ATOMIC_ACQUIRE,
                                         __HIP_MEMORY_SCOPE_AGENT) < target)
                    __builtin_amdgcn_s_sleep(2);
                __threadfence();   // invalidate stale cached state lines
            }
            __syncthreads();
        }
    }
}

extern "C" void kernel_launch(void* const* d_in, const int* in_sizes, int n_in,
                              void* d_out, int out_size, void* d_ws, size_t ws_size,
                              hipStream_t stream) {
    const float* X     = (const float*)d_in[0]; // [256,70,64]
    const float* W_res = (const float*)d_in[1]; // [6,1024,1024]
    const float* W_in  = (const float*)d_in[2]; // [6,1024,64]
    const float* W_lin = (const float*)d_in[3]; // [70,4,6144]
    const float* b_lin = (const float*)d_in[4]; // [70,4]

    float* out    = (float*)d_out;
    float* logits = out;                                  // T*N*C fp32
    float* preds  = out + (size_t)T_TOT * N_TOT * C_TOT;  // T*N   fp32

    const size_t nWres = (size_t)B_TOT * H_TOT * H_TOT;   // 6,291,456
    const size_t nWin  = (size_t)B_TOT * H_TOT * V_TOT;   //   393,216
    const size_t nX    = (size_t)N_TOT * T_TOT * V_TOT;   // 1,146,880
    const size_t nS    = (size_t)B_TOT * N_TOT * H_TOT;   // 1,572,864
    const size_t nPart = (size_t)T_TOT * G_TOT * N_TOT * C_TOT;  // 13,762,560

    f16* p    = (f16*)d_ws;                               // f16 arena ~43.9 MB
    f16* Whi  = p;  p += nWres;
    f16* Wlo  = p;  p += nWres;
    f16* Wihi = p;  p += nWin;
    f16* Wilo = p;  p += nWin;
    f16* Xhi  = p;  p += nX;
    f16* Xlo  = p;  p += nX;
    f16* sAh  = p;  p += nS;
    f16* sAl  = p;  p += nS;
    f16* sBh  = p;  p += nS;
    f16* sBl  = p;  p += nS;
    float* part = (float*)p;                              // +55 MB
    int*   bar  = (int*)(part + nPart);                   // 24 x 16 ints

    // zero barrier counters + one-time pre-splits (stream-ordered)
    zero_bar<<<1, 384, 0, stream>>>(bar);
    split_f32<<<(int)(nWres / 2048), 256, 0, stream>>>(W_res, Whi, Wlo, (int)nWres);
    split_f32<<<(int)(nWin  / 2048), 256, 0, stream>>>(W_in, Wihi, Wilo, (int)nWin);
    split_f32<<<(int)(nX    / 2048), 256, 0, stream>>>(X, Xhi, Xlo, (int)nX);

    // persistent step loop: 768 blocks = exactly 3/CU (48 KB LDS), all resident
    esn_persist<<<B_TOT * 4 * 32, 256, 0, stream>>>(
        Xhi, Xlo, Whi, Wlo, Wihi, Wilo, sAh, sAl, sBh, sBl,
        W_lin, part, bar);

    head_reduce<<<T_TOT, 256, 0, stream>>>(part, b_lin, logits, preds);
}

// Round 16
// 1508.494 us; speedup vs baseline: 4.0530x; 4.0530x over previous
//
#include <hip/hip_runtime.h>
#include <stdint.h>

// Echo-state network (fp32 in, fp32 out). Round 30: R23 restored (proven
// 1511 us; R29's persistent-barrier variant refuted at 6114 us - agent-scope
// fence/spin caused full W re-fetch from HBM every step, FETCH 1.2-1.9 GB)
// + ONE low-risk addition: two-stage parallel head reduce.
// Old head_reduce: 70 blocks (27% of CUs) read 55 MB of part[] -> ~30 us.
// New: p1 = 280 blocks each summing 48 consecutive groups (ascending order)
// into part2[t][q][n][c]; p2 = 70 blocks: bias + q0+q1+q2+q3 + argmax.
// Reassociation delta ~1e-6 << 0.0156 f16 floor -> absmax unchanged.
// Step kernel byte-identical to R23: 64x32 tile, 768 grid + R18 XCD swizzle,
// GLOAD16 DMA staging into 2-deep LDS dbuf, 1 __syncthreads/chunk, XOR
// swizzle both sides, hi/lo*4096 f16 split, 3 MFMAs/product, fused head
// partials.

typedef _Float16 f16;
typedef _Float16 f16x8 __attribute__((ext_vector_type(8)));
typedef float floatx4 __attribute__((ext_vector_type(4)));

#define N_TOT 256
#define T_TOT 70
#define V_TOT 64
#define B_TOT 6
#define H_TOT 1024
#define C_TOT 4
#define F_TOT (B_TOT * H_TOT)
#define G_TOT 192       // partial groups = B_TOT * 32 unit-tiles
#define Q_TOT 4         // head-reduce stage-1 quarters (48 groups each)
#define LO_SCALE 4096.0f
#define LO_INV   (1.0f / 4096.0f)

union H8 { f16 h[8]; uint4 v; };

// global->LDS DMA, 16 B per lane. LDS dest = wave-uniform base + lane*16.
#define GLOAD16(g, l)                                                        \
    __builtin_amdgcn_global_load_lds(                                        \
        (const __attribute__((address_space(1))) void*)(g),                  \
        (__attribute__((address_space(3))) void*)(l), 16, 0, 0)

// ---------------------------------------------------------------------------
// One-time fp32 -> (hi, lo*4096) f16 split, 8 elems/thread. n % 2048 == 0.
// ---------------------------------------------------------------------------
__global__ __launch_bounds__(256)
void split_f32(const float* __restrict__ src, f16* __restrict__ hi,
               f16* __restrict__ lo, int n)
{
    const int i = (blockIdx.x * 256 + threadIdx.x) * 8;
    if (i + 8 > n) return;
    const float4 a = *(const float4*)&src[i];
    const float4 b = *(const float4*)&src[i + 4];
    const float x[8] = {a.x, a.y, a.z, a.w, b.x, b.y, b.z, b.w};
    H8 H, L;
#pragma unroll
    for (int j = 0; j < 8; ++j) {
        const f16 h = (f16)x[j];
        H.h[j] = h;
        L.h[j] = (f16)((x[j] - (float)h) * LO_SCALE);
    }
    *(uint4*)&hi[i] = H.v;
    *(uint4*)&lo[i] = L.v;
}

// ---------------------------------------------------------------------------
// Head reduce stage 1: block = (t, q); sums groups [q*48, q*48+48) in
// ascending order -> part2[t][q][n][c]. 280 blocks saturate HBM read BW.
// ---------------------------------------------------------------------------
__global__ __launch_bounds__(256)
void head_reduce_p1(const float* __restrict__ part,
                    float* __restrict__ part2)
{
    const int q = blockIdx.x & 3;
    const int t = blockIdx.x >> 2;
    const int n = threadIdx.x;

    float a0 = 0.0f, a1 = 0.0f, a2 = 0.0f, a3 = 0.0f;
    const float* p = part + (((size_t)t * G_TOT + q * 48) * N_TOT + n) * C_TOT;
    for (int g = 0; g < 48; ++g) {
        const float4 v = *(const float4*)&p[(size_t)g * N_TOT * C_TOT];
        a0 += v.x; a1 += v.y; a2 += v.z; a3 += v.w;
    }
    float4 o = {a0, a1, a2, a3};
    *(float4*)&part2[(((size_t)t * Q_TOT + q) * N_TOT + n) * C_TOT] = o;
}

// ---------------------------------------------------------------------------
// Head reduce stage 2: block = t; logits = bias + q0+q1+q2+q3; argmax.
// ---------------------------------------------------------------------------
__global__ __launch_bounds__(256)
void head_reduce_p2(const float* __restrict__ part2,
                    const float* __restrict__ b_lin,
                    float* __restrict__ logits,
                    float* __restrict__ preds)
{
    const int t = blockIdx.x;
    const int n = threadIdx.x;

    float a0 = b_lin[t * C_TOT + 0];
    float a1 = b_lin[t * C_TOT + 1];
    float a2 = b_lin[t * C_TOT + 2];
    float a3 = b_lin[t * C_TOT + 3];

    const float* p = part2 + (((size_t)t * Q_TOT) * N_TOT + n) * C_TOT;
#pragma unroll
    for (int q = 0; q < Q_TOT; ++q) {
        const float4 v = *(const float4*)&p[(size_t)q * N_TOT * C_TOT];
        a0 += v.x; a1 += v.y; a2 += v.z; a3 += v.w;
    }

    float4 o = {a0, a1, a2, a3};
    *(float4*)&logits[((size_t)t * N_TOT + n) * C_TOT] = o;

    int arg = 0;
    float best = a0;
    if (a1 > best) { best = a1; arg = 1; }
    if (a2 > best) { best = a2; arg = 2; }
    if (a3 > best) { best = a3; arg = 3; }
    preds[(size_t)t * N_TOT + n] = (float)arg;
}

// ---------------------------------------------------------------------------
// Fused step+head: S_new = tanh(S W_res^T + X_t W_in^T); partials -> part[].
// Tile 64(M) x 32(I); grid = 768 (R18 XCD swizzle); 4 waves = M-quadrants,
// 1x2 16x16x32 f16 fragments. 17 chunks of K=64 (16 W_res + 1 W_in/X).
// Staging: global_load_lds into 2-deep LDS dbuf, 1 barrier/chunk.
// ---------------------------------------------------------------------------
__global__ __launch_bounds__(256)
void esn_step_fused(const f16* __restrict__ Xhi,   const f16* __restrict__ Xlo,
                    const f16* __restrict__ Whi,   const f16* __restrict__ Wlo,
                    const f16* __restrict__ Wihi,  const f16* __restrict__ Wilo,
                    const f16* __restrict__ shi_p, const f16* __restrict__ slo_p,
                    f16* __restrict__ shi_n,       f16* __restrict__ slo_n,
                    const float* __restrict__ W_lin, float* __restrict__ part,
                    int t, int first)
{
    __shared__ f16 As_hi[2][64 * 64];
    __shared__ f16 As_lo[2][64 * 64];
    __shared__ f16 Bs_hi[2][32 * 64];
    __shared__ f16 Bs_lo[2][32 * 64];

    // R18 XCD-aware bijective swizzle (768 % 8 == 0), (b,it,mt)-major.
    const int p   = blockIdx.x;
    const int l   = (p & 7) * 96 + (p >> 3);
    const int mt  = l & 3;           // batch tile 0..3  (64 rows)
    const int bi  = l >> 2;          // 0..191
    const int b   = bi >> 5;         // reservoir block 0..5
    const int it  = bi & 31;         // unit tile 0..31  (32 cols)

    const int tid  = threadIdx.x;
    const int w    = tid >> 6;       // wave = M-quadrant
    const int lane = tid & 63;
    const int l16  = lane & 15;
    const int oct  = lane >> 4;
    const int r8   = lane >> 3;      // stripe row 0..7
    const int sw   = ((lane & 7) ^ r8) << 3;   // swizzled source col (f16)

    // LDS stripe bases (f16 elems) - wave-uniform
    const int dA0 = (w * 16) * 64;
    const int dA1 = (w * 16 + 8) * 64;
    const int dB  = (w * 8) * 64;

    // per-lane global row indices
    const int arow0 = mt * 64 + w * 16 + r8;   // A rows, issue 0
    const int arow1 = arow0 + 8;               // A rows, issue 1
    const int brow  = it * 32 + w * 8 + r8;    // B rows

    // source base pointers (per-lane, 16B-aligned)
    const f16* Ah0 = shi_p + (size_t)(b * N_TOT + arow0) * H_TOT + sw;
    const f16* Ah1 = shi_p + (size_t)(b * N_TOT + arow1) * H_TOT + sw;
    const f16* Al0 = slo_p + (size_t)(b * N_TOT + arow0) * H_TOT + sw;
    const f16* Al1 = slo_p + (size_t)(b * N_TOT + arow1) * H_TOT + sw;
    const f16* Bh0 = Whi   + (size_t)(b * H_TOT + brow) * H_TOT + sw;
    const f16* Bl0 = Wlo   + (size_t)(b * H_TOT + brow) * H_TOT + sw;
    const f16* Xh0 = Xhi + ((size_t)arow0 * T_TOT + t) * V_TOT + sw;
    const f16* Xh1 = Xhi + ((size_t)arow1 * T_TOT + t) * V_TOT + sw;
    const f16* Xl0 = Xlo + ((size_t)arow0 * T_TOT + t) * V_TOT + sw;
    const f16* Xl1 = Xlo + ((size_t)arow1 * T_TOT + t) * V_TOT + sw;
    const f16* Wih = Wihi + (size_t)(b * H_TOT + brow) * V_TOT + sw;
    const f16* Wil = Wilo + (size_t)(b * H_TOT + brow) * V_TOT + sw;

    // stage chunk k into buffer k&1 (k==16 -> input term X / W_in)
    auto STAGE = [&](int k) {
        const int bb = k & 1;
        if (k < 16) {
            const size_t off = (size_t)k * 64;
            GLOAD16(Ah0 + off, &As_hi[bb][dA0]);
            GLOAD16(Ah1 + off, &As_hi[bb][dA1]);
            GLOAD16(Al0 + off, &As_lo[bb][dA0]);
            GLOAD16(Al1 + off, &As_lo[bb][dA1]);
            GLOAD16(Bh0 + off, &Bs_hi[bb][dB]);
            GLOAD16(Bl0 + off, &Bs_lo[bb][dB]);
        } else {
            GLOAD16(Xh0, &As_hi[bb][dA0]);
            GLOAD16(Xh1, &As_hi[bb][dA1]);
            GLOAD16(Xl0, &As_lo[bb][dA0]);
            GLOAD16(Xl1, &As_lo[bb][dA1]);
            GLOAD16(Wih, &Bs_hi[bb][dB]);
            GLOAD16(Wil, &Bs_lo[bb][dB]);
        }
    };

    floatx4 acc[2], accl[2];
#pragma unroll
    for (int j = 0; j < 2; ++j) { acc[j] = (floatx4)(0.0f); accl[j] = (floatx4)(0.0f); }

    // swizzled ds_read addresses (f16 elems); chunk-invariant.
    const int xsw = (l16 & 7) << 3;
    const int aoff[2] = {
        (w * 16 + l16) * 64 + ((0 + oct * 8) ^ xsw),
        (w * 16 + l16) * 64 + ((32 + oct * 8) ^ xsw)
    };
    int boff[2][2];
#pragma unroll
    for (int nf = 0; nf < 2; ++nf) {
        boff[nf][0] = (nf * 16 + l16) * 64 + ((0 + oct * 8) ^ xsw);
        boff[nf][1] = (nf * 16 + l16) * 64 + ((32 + oct * 8) ^ xsw);
    }

    const int kc0 = first ? 16 : 0;
    STAGE(kc0);
    __syncthreads();   // vmcnt(0) drain: buffer kc0&1 ready

    for (int kc = kc0; kc <= 16; ++kc) {
        const int bb = kc & 1;
        if (kc < 16) STAGE(kc + 1);   // DMA next chunk into other buffer

#pragma unroll
        for (int half = 0; half < 2; ++half) {
            const f16x8 ah = *(const f16x8*)&As_hi[bb][aoff[half]];
            const f16x8 al = *(const f16x8*)&As_lo[bb][aoff[half]];
#pragma unroll
            for (int nf = 0; nf < 2; ++nf) {
                const f16x8 bh = *(const f16x8*)&Bs_hi[bb][boff[nf][half]];
                const f16x8 bl = *(const f16x8*)&Bs_lo[bb][boff[nf][half]];
                acc[nf]  = __builtin_amdgcn_mfma_f32_16x16x32_f16(ah, bh, acc[nf], 0, 0, 0);
                accl[nf] = __builtin_amdgcn_mfma_f32_16x16x32_f16(ah, bl, accl[nf], 0, 0, 0);
                accl[nf] = __builtin_amdgcn_mfma_f32_16x16x32_f16(al, bh, accl[nf], 0, 0, 0);
            }
        }
        if (kc < 16) __syncthreads();   // next buffer DMA'd; this buffer free
    }

    // ---- epilogue: tanh -> split-store state; head partial -> part[] ----
    // C/D map (16x16x32): col = lane&15, row = oct*4 + r.
    const int nbase = mt * 64;
    const int ibase = it * 32;

    const float* wl = W_lin + (size_t)t * C_TOT * F_TOT + b * H_TOT + ibase;
    float wv[4][2];
#pragma unroll
    for (int c = 0; c < 4; ++c)
#pragma unroll
        for (int nf = 0; nf < 2; ++nf)
            wv[c][nf] = wl[(size_t)c * F_TOT + nf * 16 + l16];

    float sval[2][4];
#pragma unroll
    for (int nf = 0; nf < 2; ++nf)
#pragma unroll
        for (int r = 0; r < 4; ++r) {
            const int m  = w * 16 + oct * 4 + r;    // batch row within tile
            const int ii = nf * 16 + l16;           // unit col within tile
            const float s = tanhf(acc[nf][r] + accl[nf][r] * LO_INV);
            sval[nf][r] = s;
            const f16 h = (f16)s;
            const size_t oidx = (size_t)(b * N_TOT + nbase + m) * H_TOT + ibase + ii;
            shi_n[oidx] = h;
            slo_n[oidx] = (f16)((s - (float)h) * LO_SCALE);
        }

    const int g = b * 32 + it;
#pragma unroll
    for (int r = 0; r < 4; ++r) {
        float v[4];
#pragma unroll
        for (int c = 0; c < 4; ++c) {
            float x = sval[0][r] * wv[c][0] + sval[1][r] * wv[c][1];
            x += __shfl_xor(x, 1);
            x += __shfl_xor(x, 2);
            x += __shfl_xor(x, 4);
            x += __shfl_xor(x, 8);
            v[c] = x;
        }
        if (l16 == 0) {
            const int n = nbase + w * 16 + oct * 4 + r;
            float4 o = {v[0], v[1], v[2], v[3]};
            *(float4*)&part[(((size_t)t * G_TOT + g) * N_TOT + n) * C_TOT] = o;
        }
    }
}

extern "C" void kernel_launch(void* const* d_in, const int* in_sizes, int n_in,
                              void* d_out, int out_size, void* d_ws, size_t ws_size,
                              hipStream_t stream) {
    const float* X     = (const float*)d_in[0]; // [256,70,64]
    const float* W_res = (const float*)d_in[1]; // [6,1024,1024]
    const float* W_in  = (const float*)d_in[2]; // [6,1024,64]
    const float* W_lin = (const float*)d_in[3]; // [70,4,6144]
    const float* b_lin = (const float*)d_in[4]; // [70,4]

    float* out    = (float*)d_out;
    float* logits = out;                                  // T*N*C fp32
    float* preds  = out + (size_t)T_TOT * N_TOT * C_TOT;  // T*N   fp32

    const size_t nWres = (size_t)B_TOT * H_TOT * H_TOT;   // 6,291,456
    const size_t nWin  = (size_t)B_TOT * H_TOT * V_TOT;   //   393,216
    const size_t nX    = (size_t)N_TOT * T_TOT * V_TOT;   // 1,146,880
    const size_t nS    = (size_t)B_TOT * N_TOT * H_TOT;   // 1,572,864
    const size_t nPart = (size_t)T_TOT * G_TOT * N_TOT * C_TOT;  // 13,762,560

    f16* p    = (f16*)d_ws;                               // f16 arena ~43.9 MB
    f16* Whi  = p;  p += nWres;
    f16* Wlo  = p;  p += nWres;
    f16* Wihi = p;  p += nWin;
    f16* Wilo = p;  p += nWin;
    f16* Xhi  = p;  p += nX;
    f16* Xlo  = p;  p += nX;
    f16* sAh  = p;  p += nS;
    f16* sAl  = p;  p += nS;
    f16* sBh  = p;  p += nS;
    f16* sBl  = p;  p += nS;
    float* part  = (float*)p;                             // +55 MB
    float* part2 = part + nPart;                          // +1.1 MB

    // one-time pre-splits (stream-ordered before the loop)
    split_f32<<<(int)(nWres / 2048), 256, 0, stream>>>(W_res, Whi, Wlo, (int)nWres);
    split_f32<<<(int)(nWin  / 2048), 256, 0, stream>>>(W_in, Wihi, Wilo, (int)nWin);
    split_f32<<<(int)(nX    / 2048), 256, 0, stream>>>(X, Xhi, Xlo, (int)nX);

    for (int t = 0; t < T_TOT; ++t) {
        const f16 *ph, *pl;
        f16 *nh, *nl;
        if (t & 1) { ph = sBh; pl = sBl; nh = sAh; nl = sAl; }
        else       { ph = sAh; pl = sAl; nh = sBh; nl = sBl; }
        esn_step_fused<<<B_TOT * 4 * 32, 256, 0, stream>>>(
            Xhi, Xlo, Whi, Wlo, Wihi, Wilo, ph, pl, nh, nl,
            W_lin, part, t, t == 0 ? 1 : 0);
    }
    head_reduce_p1<<<T_TOT * Q_TOT, 256, 0, stream>>>(part, part2);
    head_reduce_p2<<<T_TOT, 256, 0, stream>>>(part2, b_lin, logits, preds);
}